// Round 10
// baseline (852.458 us; speedup 1.0000x reference)
//
#include <hip/hip_runtime.h>

// Batched Jacobi diffusion, B=8, 128x128, iters=1000. One 1024-thread block
// per batch. Wave-strip layout (r9): each of 16 waves owns 8 full grid rows;
// lane owns a float2 column pair (64 lanes x 2 cols = 128 cols).
//  - horizontal: DPP wave_shr:1/wave_shl:1, grid-edge clamp via DPP `old`
//  - vertical halos: float2 double-buffered LDS rows
// Round 10: NO __syncthreads in the main loop. Wave w syncs only with waves
// w+-1 through per-wave LDS sequence flags (relaxed poll + acquire fence /
// release store). flag[w+-1] >= it certifies both "state-it halos published"
// and "state-(it-1) halos consumed" -> double buffer safe at drift <= 1.
// Waves de-phase and pipeline instead of re-locksteping every iteration
// (the r1-r9 invariant ~1800 cyc/iter floor).

#define GH 128
#define GW 128
#define NW 16      // waves per block
#define RPW 8      // rows per wave
#define NT 1024

__device__ __forceinline__ float dpp_shr1(float old_v, float src) {
    // lane l gets lane l-1's src; lane 0 (invalid) gets old_v
    return __int_as_float(__builtin_amdgcn_update_dpp(
        __float_as_int(old_v), __float_as_int(src), 0x138, 0xf, 0xf, false));
}
__device__ __forceinline__ float dpp_shl1(float old_v, float src) {
    // lane l gets lane l+1's src; lane 63 (invalid) gets old_v
    return __int_as_float(__builtin_amdgcn_update_dpp(
        __float_as_int(old_v), __float_as_int(src), 0x130, 0xf, 0xf, false));
}

__global__ void __launch_bounds__(NT)
jacobi_flux_kernel(const float* __restrict__ k_all,
                   const int* __restrict__ iters_p,
                   float* __restrict__ out)
{
    __shared__ __align__(16) float2 sTop[2][NW][64];   // 16 KB
    __shared__ __align__(16) float2 sBot[2][NW][64];   // 16 KB
    __shared__ float sPad[12320];   // occupancy limiter (guarantees 1 block/CU);
                                    // sPad[0..15] doubles as the wave flags
    int* sFlag = (int*)sPad;

    const int b   = blockIdx.x;
    const int tid = threadIdx.x;
    const int l   = tid & 63;           // lane
    const int w   = tid >> 6;           // wave 0..15
    const int R0  = w * RPW;            // first grid row of my strip
    const int c0  = l * 2;              // first grid col of my pair
    const float* kb = k_all + b * GH * GW;
    const int iters = *iters_p;

    const int wUp = (w == 0)      ? 0      : w - 1;   // self => poll trivially true
    const int wDn = (w == NW - 1) ? NW - 1 : w + 1;
    const bool gTop = (w == 0);
    const bool gBot = (w == NW - 1);

    // ---- one-time: normalized face conductivities (float2 per row) ----
    float2 rN[RPW], rS[RPW], rW_[RPW], rE_[RPW];
    #pragma unroll
    for (int i = 0; i < RPW; ++i) {
        const int r  = R0 + i;
        const int ru = (r == 0)      ? 0      : r - 1;
        const int rd = (r == GH - 1) ? GH - 1 : r + 1;
        float v[2][4];
        #pragma unroll
        for (int jj = 0; jj < 2; ++jj) {
            const int c  = c0 + jj;
            const int cl = (c == 0)      ? 0      : c - 1;
            const int cr = (c == GW - 1) ? GW - 1 : c + 1;
            float kc = kb[r * GW + c];
            float kn = 0.5f * (kc + kb[ru * GW + c]);
            float ks = 0.5f * (kc + kb[rd * GW + c]);
            float kw = 0.5f * (kc + kb[r * GW + cl]);
            float ke = 0.5f * (kc + kb[r * GW + cr]);
            float inv = 1.0f / (kn + ks + kw + ke);
            v[jj][0] = kn * inv; v[jj][1] = ks * inv;
            v[jj][2] = kw * inv; v[jj][3] = ke * inv;
        }
        rN[i]  = make_float2(v[0][0], v[1][0]);
        rS[i]  = make_float2(v[0][1], v[1][1]);
        rW_[i] = make_float2(v[0][2], v[1][2]);
        rE_[i] = make_float2(v[0][3], v[1][3]);
    }

    // ---- state ----
    float2 A[RPW], B[RPW];
    #pragma unroll
    for (int i = 0; i < RPW; ++i)
        A[i] = (R0 + i == 0) ? make_float2(1.0f, 1.0f) : make_float2(0.0f, 0.0f);

    if (tid < NW) sFlag[tid] = 0;       // state 0 published (after barrier)
    sTop[0][w][l] = A[0];
    sBot[0][w][l] = A[RPW - 1];
    __syncthreads();                    // ONE barrier, ever

    auto step = [&](const float2 (&src)[RPW], float2 (&dst)[RPW],
                    int rp, int wp, int it) {
        // wait for neighbor waves to have published state `it`
        if (it > 0) {
            while (__hip_atomic_load(&sFlag[wUp], __ATOMIC_RELAXED,
                                     __HIP_MEMORY_SCOPE_WORKGROUP) < it ||
                   __hip_atomic_load(&sFlag[wDn], __ATOMIC_RELAXED,
                                     __HIP_MEMORY_SCOPE_WORKGROUP) < it) {}
            __builtin_amdgcn_fence(__ATOMIC_ACQUIRE, "workgroup");
        }
        // vertical halos (state it)
        float2 hu = sBot[rp][wUp][l];   // grid row R0-1
        float2 hd = sTop[rp][wDn][l];   // grid row R0+RPW

        // horizontal neighbors via DPP; `old` = clamp value -> edges free
        float lfv[RPW], rtv[RPW];
        #pragma unroll
        for (int i = 0; i < RPW; ++i) {
            lfv[i] = dpp_shr1(src[i].x, src[i].y);  // col c0-1
            rtv[i] = dpp_shl1(src[i].y, src[i].x);  // col c0+2
        }

        #pragma unroll
        for (int i = 0; i < RPW; ++i) {
            float upx = (i == 0)       ? hu.x : src[i - 1].x;
            float upy = (i == 0)       ? hu.y : src[i - 1].y;
            float dnx = (i == RPW - 1) ? hd.x : src[i + 1].x;
            float dny = (i == RPW - 1) ? hd.y : src[i + 1].y;
            dst[i].x = fmaf(rN[i].x, upx,
                       fmaf(rS[i].x, dnx,
                       fmaf(rW_[i].x, lfv[i], rE_[i].x * src[i].y)));
            dst[i].y = fmaf(rN[i].y, upy,
                       fmaf(rS[i].y, dny,
                       fmaf(rW_[i].y, src[i].x, rE_[i].y * rtv[i])));
        }
        if (gTop) dst[0]       = make_float2(1.0f, 1.0f);   // Dirichlet row 0
        if (gBot) dst[RPW - 1] = make_float2(0.0f, 0.0f);   // Dirichlet row 127

        // publish state it+1 halos, then release the flag
        sTop[wp][w][l] = dst[0];
        sBot[wp][w][l] = dst[RPW - 1];
        if (l == 0)
            __hip_atomic_store(&sFlag[w], it + 1, __ATOMIC_RELEASE,
                               __HIP_MEMORY_SCOPE_WORKGROUP);
    };

    const int nPairs = iters >> 1;
    for (int it = 0; it < nPairs; ++it) {
        step(A, B, 0, 1, 2 * it);
        step(B, A, 1, 0, 2 * it + 1);
    }
    if (iters & 1) {
        step(A, B, 0, 1, iters - 1);
        #pragma unroll
        for (int i = 0; i < RPW; ++i) A[i] = B[i];
    }

    // ---- flux at row 64: wave 8 holds rows 64..71 (A[0]=r64, A[1]=r65) ----
    // Only wave-8 registers needed -> no block sync required.
    if (w == 8) {
        float partial = kb[64 * GW + c0]     * (A[1].x - A[0].x)
                      + kb[64 * GW + c0 + 1] * (A[1].y - A[0].y);
        #pragma unroll
        for (int off = 32; off > 0; off >>= 1)
            partial += __shfl_down(partial, off, 64);
        if (l == 0) out[b] = -partial;
    }
}

extern "C" void kernel_launch(void* const* d_in, const int* in_sizes, int n_in,
                              void* d_out, int out_size, void* d_ws, size_t ws_size,
                              hipStream_t stream)
{
    const float* k     = (const float*)d_in[0];
    const int*   iters = (const int*)d_in[1];
    float*       out   = (float*)d_out;
    jacobi_flux_kernel<<<dim3(8), dim3(NT), 0, stream>>>(k, iters, out);
}

// Round 11
// 836.930 us; speedup vs baseline: 1.0186x; 1.0186x over previous
//
#include <hip/hip_runtime.h>

// Batched Jacobi diffusion, B=8, 128x128, iters=1000. One 1024-thread block
// per batch. Wave-strip layout: 16 waves x 8 rows; lane owns a float2 col pair.
// Round 11: TEMPORAL BLOCKING — 2 Jacobi steps per sync. Waves exchange
// 2-row halos, compute step 1 on 10 rows (own 8 + 1 into each halo region),
// step 2 on own 8. One barrier + one halo-read latency per TWO iterations.
// r8-r10 showed duration is invariant to DS/VALU throughput (~1800 cyc/iter
// across 3x DS and 1.4x VALU variation) -> floor is the per-sync serial chain;
// halving sync events should halve it. Extra cost: +2 coeff rows, +12% fma.

#define GH 128
#define GW 128
#define NW 16      // waves per block
#define RPW 8      // rows per wave
#define NT 1024

__device__ __forceinline__ float dpp_shr1(float old_v, float src) {
    // lane l gets lane l-1's src; lane 0 (invalid) gets old_v (= left clamp)
    return __int_as_float(__builtin_amdgcn_update_dpp(
        __float_as_int(old_v), __float_as_int(src), 0x138, 0xf, 0xf, false));
}
__device__ __forceinline__ float dpp_shl1(float old_v, float src) {
    // lane l gets lane l+1's src; lane 63 (invalid) gets old_v (= right clamp)
    return __int_as_float(__builtin_amdgcn_update_dpp(
        __float_as_int(old_v), __float_as_int(src), 0x130, 0xf, 0xf, false));
}

__global__ void __launch_bounds__(NT)
jacobi_flux_kernel(const float* __restrict__ k_all,
                   const int* __restrict__ iters_p,
                   float* __restrict__ out)
{
    // [parity][wave][0..1][lane]: sTop rows R0,R0+1; sBot rows R0+6,R0+7
    __shared__ __align__(16) float2 sTop[2][NW][2][64];   // 16 KB
    __shared__ __align__(16) float2 sBot[2][NW][2][64];   // 16 KB
    __shared__ float sPad[13312];   // 52 KB: forces 1 block/CU occupancy target

    const int b   = blockIdx.x;
    const int tid = threadIdx.x;
    const int l   = tid & 63;           // lane
    const int w   = tid >> 6;           // wave 0..15
    const int R0  = w * RPW;
    const int c0  = l * 2;
    const float* kb = k_all + b * GH * GW;
    const int iters = *iters_p;

    const int wUp = (w == 0)      ? 0      : w - 1;   // self-read: finite garbage, unused
    const int wDn = (w == NW - 1) ? NW - 1 : w + 1;
    const bool gTop = (w == 0);
    const bool gBot = (w == NW - 1);

    // ---- coefficients for grid rows R0-1 .. R0+8 (10 rows, clamped) ----
    // CN[i] etc. belong to grid row R0-1+i.
    float2 CN[RPW + 2], CS[RPW + 2], CW[RPW + 2], CE[RPW + 2];
    #pragma unroll
    for (int i = 0; i < RPW + 2; ++i) {
        int r = R0 - 1 + i;
        r = (r < 0) ? 0 : (r > GH - 1 ? GH - 1 : r);   // clamp (values unused at edges)
        const int ru = (r == 0)      ? 0      : r - 1;
        const int rd = (r == GH - 1) ? GH - 1 : r + 1;
        float v[2][4];
        #pragma unroll
        for (int jj = 0; jj < 2; ++jj) {
            const int c  = c0 + jj;
            const int cl = (c == 0)      ? 0      : c - 1;
            const int cr = (c == GW - 1) ? GW - 1 : c + 1;
            float kc = kb[r * GW + c];
            float kn = 0.5f * (kc + kb[ru * GW + c]);
            float ks = 0.5f * (kc + kb[rd * GW + c]);
            float kw = 0.5f * (kc + kb[r * GW + cl]);
            float ke = 0.5f * (kc + kb[r * GW + cr]);
            float inv = 1.0f / (kn + ks + kw + ke);
            v[jj][0] = kn * inv; v[jj][1] = ks * inv;
            v[jj][2] = kw * inv; v[jj][3] = ke * inv;
        }
        CN[i] = make_float2(v[0][0], v[1][0]);
        CS[i] = make_float2(v[0][1], v[1][1]);
        CW[i] = make_float2(v[0][2], v[1][2]);
        CE[i] = make_float2(v[0][3], v[1][3]);
    }

    // ---- state: own 8 rows ----
    float2 A[RPW];
    #pragma unroll
    for (int i = 0; i < RPW; ++i)
        A[i] = (R0 + i == 0) ? make_float2(1.0f, 1.0f) : make_float2(0.0f, 0.0f);

    // prime parity 0
    sTop[0][w][0][l] = A[0];  sTop[0][w][1][l] = A[1];
    sBot[0][w][0][l] = A[6];  sBot[0][w][1][l] = A[7];
    __syncthreads();

    // one Jacobi application on a row: dst = CN*up + CS*dn + CW*lf + CE*rt
    auto apply = [&](const float2& cc, const float2& up, const float2& dn,
                     const float2& cN, const float2& cS,
                     const float2& cW, const float2& cE) -> float2 {
        float lf = dpp_shr1(cc.x, cc.y);
        float rt = dpp_shl1(cc.y, cc.x);
        float2 r;
        r.x = fmaf(cN.x, up.x, fmaf(cS.x, dn.x, fmaf(cW.x, lf,   cE.x * cc.y)));
        r.y = fmaf(cN.y, up.y, fmaf(cS.y, dn.y, fmaf(cW.y, cc.x, cE.y * rt)));
        return r;
    };

    // super-step: two Jacobi iterations, one sync
    auto super = [&](int p) {
        // 2-row halos (state n), issued first
        float2 E0  = sBot[p][wUp][0][l];   // grid row R0-2
        float2 E1  = sBot[p][wUp][1][l];   // grid row R0-1
        float2 E10 = sTop[p][wDn][0][l];   // grid row R0+8
        float2 E11 = sTop[p][wDn][1][l];   // grid row R0+9

        // step 1: T1[i] = state n+1 at grid row R0-1+i, i=0..9
        float2 T1[RPW + 2];
        T1[0] = apply(E1,  E0,  A[0], CN[0], CS[0], CW[0], CE[0]);
        T1[1] = apply(A[0], E1, A[1], CN[1], CS[1], CW[1], CE[1]);
        #pragma unroll
        for (int i = 2; i < RPW; ++i)
            T1[i] = apply(A[i-1], A[i-2], A[i], CN[i], CS[i], CW[i], CE[i]);
        T1[RPW]     = apply(A[7], A[6], E10, CN[RPW],   CS[RPW],   CW[RPW],   CE[RPW]);
        T1[RPW + 1] = apply(E10,  A[7], E11, CN[RPW+1], CS[RPW+1], CW[RPW+1], CE[RPW+1]);
        if (gTop) T1[1]   = make_float2(1.0f, 1.0f);   // grid row 0 (T1[0] unused)
        if (gBot) T1[RPW] = make_float2(0.0f, 0.0f);   // grid row 127 (T1[9] unused)

        // step 2: A[j] = state n+2 at grid row R0+j, j=0..7
        #pragma unroll
        for (int j = 0; j < RPW; ++j)
            A[j] = apply(T1[j+1], T1[j], T1[j+2], CN[j+1], CS[j+1], CW[j+1], CE[j+1]);
        if (gTop) A[0] = make_float2(1.0f, 1.0f);
        if (gBot) A[7] = make_float2(0.0f, 0.0f);

        // publish state n+2 into other parity
        const int q = p ^ 1;
        sTop[q][w][0][l] = A[0];  sTop[q][w][1][l] = A[1];
        sBot[q][w][0][l] = A[6];  sBot[q][w][1][l] = A[7];
        __syncthreads();
    };

    const int nSuper = iters >> 1;
    int p = 0;
    for (int s = 0; s < nSuper; ++s) {
        super(p);
        p ^= 1;
    }
    if (iters & 1) {
        // one final single step (reads 1-row halos from parity p)
        float2 hu = sBot[p][wUp][1][l];   // grid row R0-1
        float2 hd = sTop[p][wDn][0][l];   // grid row R0+8
        float2 T[RPW];
        T[0] = apply(A[0], hu, A[1], CN[1], CS[1], CW[1], CE[1]);
        #pragma unroll
        for (int i = 1; i < RPW - 1; ++i)
            T[i] = apply(A[i], A[i-1], A[i+1], CN[i+1], CS[i+1], CW[i+1], CE[i+1]);
        T[RPW-1] = apply(A[7], A[6], hd, CN[RPW], CS[RPW], CW[RPW], CE[RPW]);
        if (gTop) T[0] = make_float2(1.0f, 1.0f);
        if (gBot) T[RPW-1] = make_float2(0.0f, 0.0f);
        #pragma unroll
        for (int i = 0; i < RPW; ++i) A[i] = T[i];
    }

    // ---- flux at row 64: wave 8 holds rows 64..71 (A[0]=r64, A[1]=r65) ----
    if (w == 8) {
        float partial = kb[64 * GW + c0]     * (A[1].x - A[0].x)
                      + kb[64 * GW + c0 + 1] * (A[1].y - A[0].y);
        #pragma unroll
        for (int off = 32; off > 0; off >>= 1)
            partial += __shfl_down(partial, off, 64);
        if (l == 0) out[b] = -partial;
    }
    // keep sPad live so the LDS occupancy limiter isn't elided
    if (tid == NT - 1) sPad[0] = (float)iters;
    if (out[b] == 1e30f) out[b] += sPad[0];   // never true; defeats DCE
}

extern "C" void kernel_launch(void* const* d_in, const int* in_sizes, int n_in,
                              void* d_out, int out_size, void* d_ws, size_t ws_size,
                              hipStream_t stream)
{
    const float* k     = (const float*)d_in[0];
    const int*   iters = (const int*)d_in[1];
    float*       out   = (float*)d_out;
    jacobi_flux_kernel<<<dim3(8), dim3(NT), 0, stream>>>(k, iters, out);
}

// Round 12
// 648.029 us; speedup vs baseline: 1.3155x; 1.2915x over previous
//
#include <hip/hip_runtime.h>

// Batched Jacobi diffusion, B=8, 128x128, iters=1000. One 1024-thread block
// per batch. Wave-strip layout: 16 waves x 8 grid rows; lane owns a float2
// column pair (64 lanes x 2 cols = 128 cols).
//  - horizontal: DPP wave_shr:1/wave_shl:1, grid-edge clamp via DPP `old`
//  - vertical halos: float2 double-buffered LDS rows, 1 barrier/iter
// Round 12: PACKED FP32 math (v_pk_fma_f32). All state/coeffs as
// ext_vector float2; stencil = 3 pk_fma + 1 pk_mul per row (replaces 8
// scalar fma). Mixed pairs (lfv,cc.x)/(cc.y,rtv) cost 2 movs/row.
// Counted VALU/thread/iter ~100 -> ~78; kernel is VALU-issue-bound
// (r8-r11: duration invariant to DS/sync count, on-CU VALUBusy 81-87%).

#define GH 128
#define GW 128
#define NW 16      // waves per block
#define RPW 8      // rows per wave
#define NT 1024

typedef float v2f __attribute__((ext_vector_type(2)));

__device__ __forceinline__ float dpp_shr1(float old_v, float src) {
    // lane l gets lane l-1's src; lane 0 (invalid) gets old_v (= left clamp)
    return __int_as_float(__builtin_amdgcn_update_dpp(
        __float_as_int(old_v), __float_as_int(src), 0x138, 0xf, 0xf, false));
}
__device__ __forceinline__ float dpp_shl1(float old_v, float src) {
    // lane l gets lane l+1's src; lane 63 (invalid) gets old_v (= right clamp)
    return __int_as_float(__builtin_amdgcn_update_dpp(
        __float_as_int(old_v), __float_as_int(src), 0x130, 0xf, 0xf, false));
}

__global__ void __launch_bounds__(NT)
jacobi_flux_kernel(const float* __restrict__ k_all,
                   const int* __restrict__ iters_p,
                   float* __restrict__ out)
{
    __shared__ __align__(16) v2f sTop[2][NW][64];   // 16 KB
    __shared__ __align__(16) v2f sBot[2][NW][64];   // 16 KB

    const int b   = blockIdx.x;
    const int tid = threadIdx.x;
    const int l   = tid & 63;           // lane
    const int w   = tid >> 6;           // wave 0..15
    const int R0  = w * RPW;            // first grid row of my strip
    const int c0  = l * 2;              // first grid col of my pair
    const float* kb = k_all + b * GH * GW;
    const int iters = *iters_p;

    const int wUp = (w == 0)      ? 0      : w - 1;
    const int wDn = (w == NW - 1) ? NW - 1 : w + 1;
    const bool gTop = (w == 0);
    const bool gBot = (w == NW - 1);

    // ---- one-time: normalized face conductivities (v2f per row) ----
    v2f rN[RPW], rS[RPW], rW_[RPW], rE_[RPW];
    #pragma unroll
    for (int i = 0; i < RPW; ++i) {
        const int r  = R0 + i;
        const int ru = (r == 0)      ? 0      : r - 1;
        const int rd = (r == GH - 1) ? GH - 1 : r + 1;
        float v[2][4];
        #pragma unroll
        for (int jj = 0; jj < 2; ++jj) {
            const int c  = c0 + jj;
            const int cl = (c == 0)      ? 0      : c - 1;
            const int cr = (c == GW - 1) ? GW - 1 : c + 1;
            float kc = kb[r * GW + c];
            float kn = 0.5f * (kc + kb[ru * GW + c]);
            float ks = 0.5f * (kc + kb[rd * GW + c]);
            float kw = 0.5f * (kc + kb[r * GW + cl]);
            float ke = 0.5f * (kc + kb[r * GW + cr]);
            float inv = 1.0f / (kn + ks + kw + ke);
            v[jj][0] = kn * inv; v[jj][1] = ks * inv;
            v[jj][2] = kw * inv; v[jj][3] = ke * inv;
        }
        rN[i]  = (v2f){v[0][0], v[1][0]};
        rS[i]  = (v2f){v[0][1], v[1][1]};
        rW_[i] = (v2f){v[0][2], v[1][2]};
        rE_[i] = (v2f){v[0][3], v[1][3]};
    }

    // ---- state ----
    v2f A[RPW], B[RPW];
    #pragma unroll
    for (int i = 0; i < RPW; ++i)
        A[i] = (R0 + i == 0) ? (v2f){1.0f, 1.0f} : (v2f){0.0f, 0.0f};

    sTop[0][w][l] = A[0];
    sBot[0][w][l] = A[RPW - 1];
    __syncthreads();

    auto step = [&](const v2f (&src)[RPW], v2f (&dst)[RPW], int rp, int wp) {
        // vertical halos (issued first; latency hides under DPP + pk chain)
        v2f hu = sBot[rp][wUp][l];   // grid row R0-1
        v2f hd = sTop[rp][wDn][l];   // grid row R0+RPW

        #pragma unroll
        for (int i = 0; i < RPW; ++i) {
            v2f cc = src[i];
            float lfv = dpp_shr1(cc.x, cc.y);   // col c0-1 (clamped at col 0)
            float rtv = dpp_shl1(cc.y, cc.x);   // col c0+2 (clamped at col 127)
            v2f lf = (v2f){lfv, cc.x};
            v2f rt = (v2f){cc.y, rtv};
            v2f up = (i == 0)       ? hu : src[i - 1];
            v2f dn = (i == RPW - 1) ? hd : src[i + 1];
            dst[i] = __builtin_elementwise_fma(rN[i], up,
                     __builtin_elementwise_fma(rS[i], dn,
                     __builtin_elementwise_fma(rW_[i], lf, rE_[i] * rt)));
        }
        if (gTop) dst[0]       = (v2f){1.0f, 1.0f};   // Dirichlet row 0
        if (gBot) dst[RPW - 1] = (v2f){0.0f, 0.0f};   // Dirichlet row 127

        sTop[wp][w][l] = dst[0];
        sBot[wp][w][l] = dst[RPW - 1];
        __syncthreads();
    };

    const int nPairs = iters >> 1;
    for (int it = 0; it < nPairs; ++it) {
        step(A, B, 0, 1);
        step(B, A, 1, 0);
    }
    if (iters & 1) {
        step(A, B, 0, 1);
        #pragma unroll
        for (int i = 0; i < RPW; ++i) A[i] = B[i];
    }

    // ---- flux at row 64: wave 8 holds rows 64..71 (A[0]=r64, A[1]=r65) ----
    if (w == 8) {
        float partial = kb[64 * GW + c0]     * (A[1].x - A[0].x)
                      + kb[64 * GW + c0 + 1] * (A[1].y - A[0].y);
        #pragma unroll
        for (int off = 32; off > 0; off >>= 1)
            partial += __shfl_down(partial, off, 64);
        if (l == 0) out[b] = -partial;
    }
}

extern "C" void kernel_launch(void* const* d_in, const int* in_sizes, int n_in,
                              void* d_out, int out_size, void* d_ws, size_t ws_size,
                              hipStream_t stream)
{
    const float* k     = (const float*)d_in[0];
    const int*   iters = (const int*)d_in[1];
    float*       out   = (float*)d_out;
    jacobi_flux_kernel<<<dim3(8), dim3(NT), 0, stream>>>(k, iters, out);
}

// Round 13
// 589.395 us; speedup vs baseline: 1.4463x; 1.0995x over previous
//
#include <hip/hip_runtime.h>

// Batched Jacobi diffusion, B=8, 128x128, iters=1000. One 1024-thread block
// per batch. Wave-strip layout: 16 waves x 8 grid rows; lane owns a float2
// column pair. VALU-issue-bound (r12: pk_fma cut 24%).
// Round 13: regrouped horizontal term to kill the mixed-pair mov builds:
//   H = pk_fma(cLR, (lfv,rtv), pk_mul(cM, cc.yx))
// with packed constants cM=(cE.x,cW.y), cLR=(cW.x,cE.y). cc.yx is a VOP3P
// op_sel half-swap (free); (lfv,rtv) are the two DPP results (adjacent
// allocation). Best case 6 issue slots/row vs 8-10 in r12.

#define GH 128
#define GW 128
#define NW 16      // waves per block
#define RPW 8      // rows per wave
#define NT 1024

typedef float v2f __attribute__((ext_vector_type(2)));

__device__ __forceinline__ float dpp_shr1(float old_v, float src) {
    // lane l gets lane l-1's src; lane 0 (invalid) gets old_v (= left clamp)
    return __int_as_float(__builtin_amdgcn_update_dpp(
        __float_as_int(old_v), __float_as_int(src), 0x138, 0xf, 0xf, false));
}
__device__ __forceinline__ float dpp_shl1(float old_v, float src) {
    // lane l gets lane l+1's src; lane 63 (invalid) gets old_v (= right clamp)
    return __int_as_float(__builtin_amdgcn_update_dpp(
        __float_as_int(old_v), __float_as_int(src), 0x130, 0xf, 0xf, false));
}

__global__ void __launch_bounds__(NT)
jacobi_flux_kernel(const float* __restrict__ k_all,
                   const int* __restrict__ iters_p,
                   float* __restrict__ out)
{
    __shared__ __align__(16) v2f sTop[2][NW][64];   // 16 KB
    __shared__ __align__(16) v2f sBot[2][NW][64];   // 16 KB

    const int b   = blockIdx.x;
    const int tid = threadIdx.x;
    const int l   = tid & 63;           // lane
    const int w   = tid >> 6;           // wave 0..15
    const int R0  = w * RPW;            // first grid row of my strip
    const int c0  = l * 2;              // first grid col of my pair
    const float* kb = k_all + b * GH * GW;
    const int iters = *iters_p;

    const int wUp = (w == 0)      ? 0      : w - 1;
    const int wDn = (w == NW - 1) ? NW - 1 : w + 1;
    const bool gTop = (w == 0);
    const bool gBot = (w == NW - 1);

    // ---- one-time: normalized face conductivities, packed for the
    //      regrouped stencil: rN, rS (vertical), cM=(cE.x,cW.y), cLR=(cW.x,cE.y)
    v2f rN[RPW], rS[RPW], cM[RPW], cLR[RPW];
    #pragma unroll
    for (int i = 0; i < RPW; ++i) {
        const int r  = R0 + i;
        const int ru = (r == 0)      ? 0      : r - 1;
        const int rd = (r == GH - 1) ? GH - 1 : r + 1;
        float v[2][4];
        #pragma unroll
        for (int jj = 0; jj < 2; ++jj) {
            const int c  = c0 + jj;
            const int cl = (c == 0)      ? 0      : c - 1;
            const int cr = (c == GW - 1) ? GW - 1 : c + 1;
            float kc = kb[r * GW + c];
            float kn = 0.5f * (kc + kb[ru * GW + c]);
            float ks = 0.5f * (kc + kb[rd * GW + c]);
            float kw = 0.5f * (kc + kb[r * GW + cl]);
            float ke = 0.5f * (kc + kb[r * GW + cr]);
            float inv = 1.0f / (kn + ks + kw + ke);
            v[jj][0] = kn * inv; v[jj][1] = ks * inv;
            v[jj][2] = kw * inv; v[jj][3] = ke * inv;
        }
        rN[i]  = (v2f){v[0][0], v[1][0]};
        rS[i]  = (v2f){v[0][1], v[1][1]};
        cM[i]  = (v2f){v[0][3], v[1][2]};   // (cE.x, cW.y) pairs with cc.yx
        cLR[i] = (v2f){v[0][2], v[1][3]};   // (cW.x, cE.y) pairs with (lfv,rtv)
    }

    // ---- state ----
    v2f A[RPW], B[RPW];
    #pragma unroll
    for (int i = 0; i < RPW; ++i)
        A[i] = (R0 + i == 0) ? (v2f){1.0f, 1.0f} : (v2f){0.0f, 0.0f};

    sTop[0][w][l] = A[0];
    sBot[0][w][l] = A[RPW - 1];
    __syncthreads();

    auto step = [&](const v2f (&src)[RPW], v2f (&dst)[RPW], int rp, int wp) {
        // vertical halos (issued first; latency hides under DPP + pk chain)
        v2f hu = sBot[rp][wUp][l];   // grid row R0-1
        v2f hd = sTop[rp][wDn][l];   // grid row R0+RPW

        #pragma unroll
        for (int i = 0; i < RPW; ++i) {
            v2f cc = src[i];
            // (lfv, rtv): two DPP results, used only as a pair
            v2f s;
            s.x = dpp_shr1(cc.x, cc.y);   // left  neighbor (clamped at col 0)
            s.y = dpp_shl1(cc.y, cc.x);   // right neighbor (clamped at col 127)
            v2f up = (i == 0)       ? hu : src[i - 1];
            v2f dn = (i == RPW - 1) ? hd : src[i + 1];
            // H = cLR*(lfv,rtv) + cM*cc.yx ; dst = rN*up + rS*dn + H
            dst[i] = __builtin_elementwise_fma(rN[i], up,
                     __builtin_elementwise_fma(rS[i], dn,
                     __builtin_elementwise_fma(cLR[i], s, cM[i] * cc.yx)));
        }
        if (gTop) dst[0]       = (v2f){1.0f, 1.0f};   // Dirichlet row 0
        if (gBot) dst[RPW - 1] = (v2f){0.0f, 0.0f};   // Dirichlet row 127

        sTop[wp][w][l] = dst[0];
        sBot[wp][w][l] = dst[RPW - 1];
        __syncthreads();
    };

    const int nPairs = iters >> 1;
    for (int it = 0; it < nPairs; ++it) {
        step(A, B, 0, 1);
        step(B, A, 1, 0);
    }
    if (iters & 1) {
        step(A, B, 0, 1);
        #pragma unroll
        for (int i = 0; i < RPW; ++i) A[i] = B[i];
    }

    // ---- flux at row 64: wave 8 holds rows 64..71 (A[0]=r64, A[1]=r65) ----
    if (w == 8) {
        float partial = kb[64 * GW + c0]     * (A[1].x - A[0].x)
                      + kb[64 * GW + c0 + 1] * (A[1].y - A[0].y);
        #pragma unroll
        for (int off = 32; off > 0; off >>= 1)
            partial += __shfl_down(partial, off, 64);
        if (l == 0) out[b] = -partial;
    }
}

extern "C" void kernel_launch(void* const* d_in, const int* in_sizes, int n_in,
                              void* d_out, int out_size, void* d_ws, size_t ws_size,
                              hipStream_t stream)
{
    const float* k     = (const float*)d_in[0];
    const int*   iters = (const int*)d_in[1];
    float*       out   = (float*)d_out;
    jacobi_flux_kernel<<<dim3(8), dim3(NT), 0, stream>>>(k, iters, out);
}